// Round 1
// baseline (249.882 us; speedup 1.0000x reference)
//
#include <hip/hip_runtime.h>
#include <hip/hip_bf16.h>

// Problem constants
#define QSTRIDE 147584   // per-sample question_rep stride (128*128*9 + 128)
#define WOFF    147456   // bias offset within question_rep row

typedef __attribute__((ext_vector_type(8))) short bf16x8;
typedef __attribute__((ext_vector_type(4))) float f32x4;

static __device__ __forceinline__ ushort f2bf(float f) {
  union { float f; unsigned u; } x; x.f = f;
  unsigned r = x.u + 0x7fffu + ((x.u >> 16) & 1u);  // RNE bf16 (finite inputs)
  return (ushort)(r >> 16);
}
static __device__ __forceinline__ unsigned pk2(ushort a, ushort b) {
  return (unsigned)a | ((unsigned)b << 16);
}

// ---------------------------------------------------------------------------
// 1) question_rep weights -> Wt[b][tap][o][ci] bf16   (tap-major for conv A-tiles)
//    thread = (b, o, ci-quarter); reads contiguous float4, writes 16B chunks
// ---------------------------------------------------------------------------
__global__ __launch_bounds__(256) void pack_w_kernel(const float* __restrict__ q,
                                                     ushort* __restrict__ wt) {
  int tid = blockIdx.x * 256 + threadIdx.x;          // 32768 threads
  int b   = tid >> 9;
  int o   = (tid >> 2) & 127;
  int qtr = tid & 3;
  int ci0 = qtr * 32;
  const float* src = q + (size_t)b * QSTRIDE + (size_t)o * 1152 + (size_t)ci0 * 9;
  size_t wbase = (size_t)b * 9 * 16384 + (size_t)o * 128 + ci0;
  for (int s = 0; s < 4; ++s) {                      // 8 ci per sub-chunk
    float v[72];
    const float4* s4 = (const float4*)(src + s * 72);
#pragma unroll
    for (int i = 0; i < 18; ++i) {
      float4 f = s4[i];
      v[4*i+0] = f.x; v[4*i+1] = f.y; v[4*i+2] = f.z; v[4*i+3] = f.w;
    }
#pragma unroll
    for (int tap = 0; tap < 9; ++tap) {
      ushort u[8];
#pragma unroll
      for (int j = 0; j < 8; ++j) u[j] = f2bf(v[j*9 + tap]);  // element (ci0+s*8+j, tap)
      uint4 pkv;
      pkv.x = pk2(u[0],u[1]); pkv.y = pk2(u[2],u[3]);
      pkv.z = pk2(u[4],u[5]); pkv.w = pk2(u[6],u[7]);
      *(uint4*)(wt + wbase + (size_t)tap * 16384 + s * 8) = pkv;
    }
  }
}

// ---------------------------------------------------------------------------
// 2) proj_w (128x256 fp32) -> bf16, same layout
// ---------------------------------------------------------------------------
__global__ __launch_bounds__(256) void pack_pw_kernel(const float* __restrict__ pw,
                                                      ushort* __restrict__ pwb) {
  int idx = blockIdx.x * 256 + threadIdx.x;          // 8192 threads * 4 elems
  float4 f = ((const float4*)pw)[idx];
  uint2 pkv;
  pkv.x = pk2(f2bf(f.x), f2bf(f.y));
  pkv.y = pk2(f2bf(f.z), f2bf(f.w));
  *(uint2*)(pwb + (size_t)idx * 4) = pkv;
}

// ---------------------------------------------------------------------------
// 3) lhs/rhs NCHW fp32 -> catT[b][p][c] bf16 (c: 0..127 lhs, 128..255 rhs)
//    lane = pixel -> coalesced reads; per-lane sequential stores (L2 combines)
// ---------------------------------------------------------------------------
__global__ __launch_bounds__(256) void tcat_kernel(const float* __restrict__ lhs,
                                                   const float* __restrict__ rhs,
                                                   ushort* __restrict__ catT) {
  int b = blockIdx.x >> 2;
  int p = ((blockIdx.x & 3) << 8) + threadIdx.x;     // 0..1023
  const float* lp = lhs + (size_t)b * 128 * 1024 + p;
  const float* rp = rhs + (size_t)b * 128 * 1024 + p;
  ushort* dst = catT + ((size_t)b * 1024 + p) * 256;
  for (int c0 = 0; c0 < 128; c0 += 8) {
    ushort u[8];
#pragma unroll
    for (int j = 0; j < 8; ++j) u[j] = f2bf(lp[(size_t)(c0 + j) * 1024]);
    uint4 pkv;
    pkv.x = pk2(u[0],u[1]); pkv.y = pk2(u[2],u[3]);
    pkv.z = pk2(u[4],u[5]); pkv.w = pk2(u[6],u[7]);
    *(uint4*)(dst + c0) = pkv;
  }
  for (int c0 = 0; c0 < 128; c0 += 8) {
    ushort u[8];
#pragma unroll
    for (int j = 0; j < 8; ++j) u[j] = f2bf(rp[(size_t)(c0 + j) * 1024]);
    uint4 pkv;
    pkv.x = pk2(u[0],u[1]); pkv.y = pk2(u[2],u[3]);
    pkv.z = pk2(u[4],u[5]); pkv.w = pk2(u[6],u[7]);
    *(uint4*)(dst + 128 + c0) = pkv;
  }
}

// ---------------------------------------------------------------------------
// 4) zero the halo of Xp[b][34][34][128] (ws is re-poisoned 0xAA every call)
// ---------------------------------------------------------------------------
__global__ __launch_bounds__(256) void zero_border_kernel(ushort* __restrict__ xp) {
  int b = blockIdx.x, t = threadIdx.x;
  if (t < 132) {
    int hp, wp;
    if (t < 34)       { hp = 0;        wp = t; }
    else if (t < 68)  { hp = 33;       wp = t - 34; }
    else if (t < 100) { hp = t - 67;   wp = 0; }     // 1..32
    else              { hp = t - 99;   wp = 33; }    // 1..32
    uint4 z = {0u,0u,0u,0u};
    uint4* dst = (uint4*)(xp + (((size_t)b * 34 + hp) * 34 + wp) * 128);
#pragma unroll
    for (int i = 0; i < 16; ++i) dst[i] = z;
  }
}

// ---------------------------------------------------------------------------
// 5) Projection GEMM: Xp[b,hp,wp,o] = sum_c pw[o][c]*catT[b][p][c] + pb[o]
//    per block: sample b, 128 px (4 h-rows), M=128, K=256
// ---------------------------------------------------------------------------
__global__ __launch_bounds__(256, 2) void proj_kernel(const ushort* __restrict__ pwb,
                                                      const ushort* __restrict__ catT,
                                                      const float* __restrict__ pb,
                                                      ushort* __restrict__ xp) {
  __shared__ ushort As[128 * 32];
  __shared__ ushort Bs[128 * 32];
  int b = blockIdx.y, tile = blockIdx.x;
  int p0 = tile * 128;
  int t = threadIdx.x;
  int lane = t & 63, wv = t >> 6;
  int m0 = (wv & 1) * 64, n0 = (wv >> 1) * 64;
  int quad = lane >> 4, li = lane & 15;
  f32x4 acc[4][4] = {};
  int r = t >> 1, hf = t & 1;
  const ushort* asrc = pwb + (size_t)r * 256 + hf * 16;
  const ushort* bsrc = catT + ((size_t)b * 1024 + p0 + r) * 256 + hf * 16;
  uint4* la = (uint4*)(As + r * 32 + hf * 16);
  uint4* lb = (uint4*)(Bs + r * 32 + hf * 16);

  for (int c0 = 0; c0 < 256; c0 += 32) {
    __syncthreads();
    { const uint4* ga = (const uint4*)(asrc + c0); la[0] = ga[0]; la[1] = ga[1];
      const uint4* gb = (const uint4*)(bsrc + c0); lb[0] = gb[0]; lb[1] = gb[1]; }
    __syncthreads();
    bf16x8 af[4], bg[4];
#pragma unroll
    for (int mi = 0; mi < 4; ++mi)
      af[mi] = *(const bf16x8*)(As + (m0 + mi*16 + li) * 32 + quad * 8);
#pragma unroll
    for (int ni = 0; ni < 4; ++ni)
      bg[ni] = *(const bf16x8*)(Bs + (n0 + ni*16 + li) * 32 + quad * 8);
#pragma unroll
    for (int mi = 0; mi < 4; ++mi)
#pragma unroll
      for (int ni = 0; ni < 4; ++ni)
        acc[mi][ni] = __builtin_amdgcn_mfma_f32_16x16x32_bf16(af[mi], bg[ni], acc[mi][ni], 0, 0, 0);
  }

#pragma unroll
  for (int mi = 0; mi < 4; ++mi) {
    int o0 = m0 + mi*16 + quad*4;
    float4 bias = *(const float4*)(pb + o0);
#pragma unroll
    for (int ni = 0; ni < 4; ++ni) {
      int p = p0 + n0 + ni*16 + li;
      int h = p >> 5, w = p & 31;
      ushort* dp = xp + (((size_t)b * 34 + h + 1) * 34 + (w + 1)) * 128 + o0;
      f32x4 a = acc[mi][ni];
      uint2 pkv;
      pkv.x = pk2(f2bf(a.x + bias.x), f2bf(a.y + bias.y));
      pkv.y = pk2(f2bf(a.z + bias.z), f2bf(a.w + bias.w));
      *(uint2*)dp = pkv;
    }
  }
}

// ---------------------------------------------------------------------------
// 6) Conv implicit GEMM: out[b,o,p] = sum_{tap,ci} Wt[b,tap,o,ci]*Xp[b,h+kh,w+kw,ci] + bias
//    K = 9 taps x 128 ci; padded Xp makes tap shifts branch-free
// ---------------------------------------------------------------------------
__global__ __launch_bounds__(256, 2) void conv_kernel(const ushort* __restrict__ wt,
                                                      const ushort* __restrict__ xp,
                                                      const float* __restrict__ q,
                                                      float* __restrict__ out) {
  __shared__ ushort As[128 * 32];
  __shared__ ushort Bs[128 * 32];
  int b = blockIdx.y, tile = blockIdx.x;
  int p0 = tile * 128, h0 = tile * 4;
  int t = threadIdx.x;
  int lane = t & 63, wv = t >> 6;
  int m0 = (wv & 1) * 64, n0 = (wv >> 1) * 64;
  int quad = lane >> 4, li = lane & 15;
  f32x4 acc[4][4] = {};
  int r = t >> 1, hf = t & 1;
  int rh = h0 + (r >> 5), rw = r & 31;               // staging pixel coords
  const ushort* wtb = wt + (size_t)b * 9 * 16384;
  const ushort* xpb = xp + (size_t)b * 34 * 34 * 128;
  uint4* la = (uint4*)(As + r * 32 + hf * 16);
  uint4* lb = (uint4*)(Bs + r * 32 + hf * 16);

  for (int tap = 0; tap < 9; ++tap) {
    int kh = tap / 3, kw = tap - kh * 3;
    const ushort* asrc = wtb + ((size_t)tap * 128 + r) * 128 + hf * 16;
    const ushort* bsrc = xpb + (((size_t)(rh + kh)) * 34 + (rw + kw)) * 128 + hf * 16;
    for (int c0 = 0; c0 < 128; c0 += 32) {
      __syncthreads();
      { const uint4* ga = (const uint4*)(asrc + c0); la[0] = ga[0]; la[1] = ga[1];
        const uint4* gb = (const uint4*)(bsrc + c0); lb[0] = gb[0]; lb[1] = gb[1]; }
      __syncthreads();
      bf16x8 af[4], bg[4];
#pragma unroll
      for (int mi = 0; mi < 4; ++mi)
        af[mi] = *(const bf16x8*)(As + (m0 + mi*16 + li) * 32 + quad * 8);
#pragma unroll
      for (int ni = 0; ni < 4; ++ni)
        bg[ni] = *(const bf16x8*)(Bs + (n0 + ni*16 + li) * 32 + quad * 8);
#pragma unroll
      for (int mi = 0; mi < 4; ++mi)
#pragma unroll
        for (int ni = 0; ni < 4; ++ni)
          acc[mi][ni] = __builtin_amdgcn_mfma_f32_16x16x32_bf16(af[mi], bg[ni], acc[mi][ni], 0, 0, 0);
    }
  }

  const float* qb = q + (size_t)b * QSTRIDE + WOFF;
  float* ob = out + (size_t)b * 128 * 1024 + p0;
#pragma unroll
  for (int mi = 0; mi < 4; ++mi) {
    int o0 = m0 + mi*16 + quad*4;
    float4 bias = *(const float4*)(qb + o0);
#pragma unroll
    for (int ni = 0; ni < 4; ++ni) {
      int pl = n0 + ni*16 + li;
      float* dp = ob + (size_t)o0 * 1024 + pl;
      f32x4 a = acc[mi][ni];
      dp[0]    = a.x + bias.x;
      dp[1024] = a.y + bias.y;
      dp[2048] = a.z + bias.z;
      dp[3072] = a.w + bias.w;
    }
  }
}

extern "C" void kernel_launch(void* const* d_in, const int* in_sizes, int n_in,
                              void* d_out, int out_size, void* d_ws, size_t ws_size,
                              hipStream_t stream) {
  const float* q   = (const float*)d_in[0];
  const float* lhs = (const float*)d_in[1];
  const float* rhs = (const float*)d_in[2];
  const float* pw  = (const float*)d_in[3];
  const float* pb  = (const float*)d_in[4];
  float* out = (float*)d_out;

  // workspace layout (73,793,536 B total)
  char* ws = (char*)d_ws;
  ushort* wt   = (ushort*)(ws);               // 21,233,664 B : Wt[b][tap][o][ci]
  ushort* pwb  = (ushort*)(ws + 21233664);    //     65,536 B : proj_w bf16
  ushort* catT = (ushort*)(ws + 21299200);    // 33,554,432 B : catT[b][p][c]
  ushort* xp   = (ushort*)(ws + 54853632);    // 18,939,904 B : Xp[b][34][34][128]

  pack_w_kernel     <<<128, 256, 0, stream>>>(q, wt);
  pack_pw_kernel    <<<32,  256, 0, stream>>>(pw, pwb);
  tcat_kernel       <<<256, 256, 0, stream>>>(lhs, rhs, catT);
  zero_border_kernel<<<64,  256, 0, stream>>>(xp);
  proj_kernel       <<<dim3(8, 64), 256, 0, stream>>>(pwb, catT, pb, xp);
  conv_kernel       <<<dim3(8, 64), 256, 0, stream>>>(wt, xp, q, out);
}

// Round 2
// 198.759 us; speedup vs baseline: 1.2572x; 1.2572x over previous
//
#include <hip/hip_runtime.h>
#include <hip/hip_bf16.h>

// Problem constants
#define QSTRIDE 147584   // per-sample question_rep stride (128*128*9 + 128)
#define WOFF    147456   // bias offset within question_rep row

typedef __attribute__((ext_vector_type(8))) short bf16x8;
typedef __attribute__((ext_vector_type(4))) float f32x4;

static __device__ __forceinline__ ushort f2bf(float f) {
  union { float f; unsigned u; } x; x.f = f;
  unsigned r = x.u + 0x7fffu + ((x.u >> 16) & 1u);  // RNE bf16 (finite inputs)
  return (ushort)(r >> 16);
}
static __device__ __forceinline__ unsigned pk2(ushort a, ushort b) {
  return (unsigned)a | ((unsigned)b << 16);
}
// async global->LDS DMA, 16B per lane; lds base must be wave-uniform
static __device__ __forceinline__ void async16(const ushort* g, ushort* l) {
  __builtin_amdgcn_global_load_lds((const __attribute__((address_space(1))) void*)g,
                                   (__attribute__((address_space(3))) void*)l, 16, 0, 0);
}

// ---------------------------------------------------------------------------
// 1) question_rep weights -> wt2[b][tap][cq][o][ci32] bf16
//    (tap,cq)-major so every conv A-tile is one contiguous 8KB chunk (DMA-able)
//    thread = (b, o, 8-ci slice): 18 float4 loads, 9 uint4 stores
// ---------------------------------------------------------------------------
__global__ __launch_bounds__(256) void pack_w_kernel(const float* __restrict__ q,
                                                     ushort* __restrict__ wt2) {
  int b    = blockIdx.x >> 3;
  int ogrp = blockIdx.x & 7;
  int t    = threadIdx.x;
  int o    = ogrp * 16 + (t >> 4);
  int ci0  = (t & 15) * 8;                 // 0..120
  int cq   = ci0 >> 5, coff = ci0 & 31;
  const float* src = q + (size_t)b * QSTRIDE + (size_t)o * 1152 + (size_t)ci0 * 9;
  float v[72];
  const float4* s4 = (const float4*)src;
#pragma unroll
  for (int i = 0; i < 18; ++i) {
    float4 f = s4[i];
    v[4*i+0] = f.x; v[4*i+1] = f.y; v[4*i+2] = f.z; v[4*i+3] = f.w;
  }
  ushort* dstb = wt2 + (size_t)b * 147456 + (size_t)cq * 4096 + o * 32 + coff;
#pragma unroll
  for (int tap = 0; tap < 9; ++tap) {
    ushort u[8];
#pragma unroll
    for (int j = 0; j < 8; ++j) u[j] = f2bf(v[j*9 + tap]);
    uint4 pkv;
    pkv.x = pk2(u[0],u[1]); pkv.y = pk2(u[2],u[3]);
    pkv.z = pk2(u[4],u[5]); pkv.w = pk2(u[6],u[7]);
    *(uint4*)(dstb + (size_t)tap * 16384) = pkv;
  }
}

// ---------------------------------------------------------------------------
// 2) proj_w (128x256 fp32) -> pwb2[cq][o][c32] bf16 (chunk-major, DMA-able)
// ---------------------------------------------------------------------------
__global__ __launch_bounds__(256) void pack_pw_kernel(const float* __restrict__ pw,
                                                      ushort* __restrict__ pwb2) {
  int tg = blockIdx.x * 256 + threadIdx.x;   // 4096 threads
  int o  = tg >> 5;
  int c0 = (tg & 31) * 8;
  const float4* s4 = (const float4*)(pw + (size_t)o * 256 + c0);
  float4 f0 = s4[0], f1 = s4[1];
  uint4 pkv;
  pkv.x = pk2(f2bf(f0.x), f2bf(f0.y)); pkv.y = pk2(f2bf(f0.z), f2bf(f0.w));
  pkv.z = pk2(f2bf(f1.x), f2bf(f1.y)); pkv.w = pk2(f2bf(f1.z), f2bf(f1.w));
  *(uint4*)(pwb2 + (size_t)(c0 >> 5) * 4096 + o * 32 + (c0 & 31)) = pkv;
}

// ---------------------------------------------------------------------------
// 3) zero the halo of xp2[b][cq][34][34][32]
// ---------------------------------------------------------------------------
__global__ __launch_bounds__(256) void zero_border_kernel(ushort* __restrict__ xp2) {
  int b = blockIdx.x, t = threadIdx.x;
  for (int idx = t; idx < 528; idx += 256) {
    int cq = idx / 132, r = idx - cq * 132;
    int hp, wp;
    if (r < 34)       { hp = 0;        wp = r; }
    else if (r < 68)  { hp = 33;       wp = r - 34; }
    else if (r < 100) { hp = r - 67;   wp = 0; }     // 1..32
    else              { hp = r - 99;   wp = 33; }    // 1..32
    uint4 z = {0u,0u,0u,0u};
    uint4* dst = (uint4*)(xp2 + (((size_t)b * 4 + cq) * 1156 + hp * 34 + wp) * 32);
#pragma unroll
    for (int i = 0; i < 4; ++i) dst[i] = z;
  }
}

// ---------------------------------------------------------------------------
// 4) Fused projection: reads lhs/rhs NCHW fp32 directly, register-transposes
//    into B-tiles, MFMA GEMM (M=128 o, N=128 px, K=256), writes xp2 bf16 NHWC.
// ---------------------------------------------------------------------------
__global__ __launch_bounds__(256, 2) void proj_kernel(const ushort* __restrict__ pwb2,
                                                      const float* __restrict__ lhs,
                                                      const float* __restrict__ rhs,
                                                      const float* __restrict__ pb,
                                                      ushort* __restrict__ xp2) {
  __shared__ ushort As[128 * 32];
  __shared__ ushort Bs[128 * 32];
  int b = blockIdx.y, tile = blockIdx.x;
  int p0 = tile * 128;
  int t = threadIdx.x;
  int lane = t & 63, wv = t >> 6;
  int m0 = (wv & 1) * 64, n0 = (wv >> 1) * 64;
  int quad = lane >> 4, li = lane & 15;
  f32x4 acc[4][4] = {};
  int cgrp = t & 3;                 // 8-channel group within 32-chunk
  int pq   = t >> 2;                // 0..63 -> pixel pair 2pq, 2pq+1

  for (int c0 = 0; c0 < 256; c0 += 32) {
    const float* src = (c0 < 128 ? lhs : rhs) + (size_t)b * 131072
                     + (size_t)((c0 & 127) + cgrp * 8) * 1024 + p0 + 2 * pq;
    // load 8 channels x 2 px, convert, transpose in-register
    ushort u0[8], u1[8];
#pragma unroll
    for (int j = 0; j < 8; ++j) {
      float2 f = *(const float2*)(src + (size_t)j * 1024);
      u0[j] = f2bf(f.x); u1[j] = f2bf(f.y);
    }
    __syncthreads();   // previous chunk fully consumed
    // A-tile DMA: 8KB contiguous chunk of pwb2
    {
      const ushort* ag = pwb2 + (size_t)(c0 >> 5) * 4096;
      async16(ag + (size_t)wv * 512 + lane * 8,       As + wv * 512);
      async16(ag + (size_t)(wv + 4) * 512 + lane * 8, As + (wv + 4) * 512);
    }
    {
      uint4 pk0, pk1;
      pk0.x = pk2(u0[0],u0[1]); pk0.y = pk2(u0[2],u0[3]);
      pk0.z = pk2(u0[4],u0[5]); pk0.w = pk2(u0[6],u0[7]);
      pk1.x = pk2(u1[0],u1[1]); pk1.y = pk2(u1[2],u1[3]);
      pk1.z = pk2(u1[4],u1[5]); pk1.w = pk2(u1[6],u1[7]);
      *(uint4*)(Bs + (size_t)(2*pq)   * 32 + cgrp * 8) = pk0;
      *(uint4*)(Bs + (size_t)(2*pq+1) * 32 + cgrp * 8) = pk1;
    }
    __syncthreads();   // drains DMA (vmcnt) + LDS stores
    bf16x8 af[4], bg[4];
#pragma unroll
    for (int mi = 0; mi < 4; ++mi)
      af[mi] = *(const bf16x8*)(As + (m0 + mi*16 + li) * 32 + quad * 8);
#pragma unroll
    for (int ni = 0; ni < 4; ++ni)
      bg[ni] = *(const bf16x8*)(Bs + (n0 + ni*16 + li) * 32 + quad * 8);
#pragma unroll
    for (int mi = 0; mi < 4; ++mi)
#pragma unroll
      for (int ni = 0; ni < 4; ++ni)
        acc[mi][ni] = __builtin_amdgcn_mfma_f32_16x16x32_bf16(af[mi], bg[ni], acc[mi][ni], 0, 0, 0);
  }

  ushort* xpb = xp2 + (size_t)b * 4 * 1156 * 32;
#pragma unroll
  for (int mi = 0; mi < 4; ++mi) {
    int o0 = m0 + mi*16 + quad*4;
    float4 bias = *(const float4*)(pb + o0);
#pragma unroll
    for (int ni = 0; ni < 4; ++ni) {
      int p = p0 + n0 + ni*16 + li;
      int h = p >> 5, w = p & 31;
      ushort* dp = xpb + ((size_t)(o0 >> 5) * 1156 + (h + 1) * 34 + (w + 1)) * 32 + (o0 & 31);
      f32x4 a = acc[mi][ni];
      uint2 pkv;
      pkv.x = pk2(f2bf(a.x + bias.x), f2bf(a.y + bias.y));
      pkv.y = pk2(f2bf(a.z + bias.z), f2bf(a.w + bias.w));
      *(uint2*)dp = pkv;
    }
  }
}

// ---------------------------------------------------------------------------
// 5) Conv implicit GEMM with global_load_lds staging.
//    K = 9 taps x 4 ci-chunks; A chunk = 8KB contiguous, B chunk = 4 rows x 2KB
// ---------------------------------------------------------------------------
__global__ __launch_bounds__(256, 2) void conv_kernel(const ushort* __restrict__ wt2,
                                                      const ushort* __restrict__ xp2,
                                                      const float* __restrict__ q,
                                                      float* __restrict__ out) {
  __shared__ ushort As[128 * 32];
  __shared__ ushort Bs[128 * 32];
  int b = blockIdx.y, tile = blockIdx.x;
  int p0 = tile * 128, h0 = tile * 4;
  int t = threadIdx.x;
  int lane = t & 63, wv = t >> 6;
  int m0 = (wv & 1) * 64, n0 = (wv >> 1) * 64;
  int quad = lane >> 4, li = lane & 15;
  f32x4 acc[4][4] = {};
  const ushort* wtb = wt2 + (size_t)b * 147456;
  const ushort* xpb = xp2 + (size_t)b * 4 * 1156 * 32;

  for (int tap = 0; tap < 9; ++tap) {
    int kh = tap / 3, kw = tap - kh * 3;
    for (int cq = 0; cq < 4; ++cq) {
      __syncthreads();   // previous chunk fully consumed
      // A: contiguous 8KB; wave wv does 1KB segments wv and wv+4
      const ushort* ag = wtb + (size_t)(tap * 4 + cq) * 4096;
      async16(ag + (size_t)wv * 512 + lane * 8,       As + wv * 512);
      async16(ag + (size_t)(wv + 4) * 512 + lane * 8, As + (wv + 4) * 512);
      // B: wave wv stages pixel row h0+wv (32 px x 64B = 2KB contiguous)
      const ushort* bgp = xpb + (size_t)((cq * 1156) + (h0 + wv + kh) * 34 + kw) * 32;
      async16(bgp + lane * 8,       Bs + wv * 1024);
      async16(bgp + 512 + lane * 8, Bs + wv * 1024 + 512);
      __syncthreads();   // drains DMA
      bf16x8 af[4], bg[4];
#pragma unroll
      for (int mi = 0; mi < 4; ++mi)
        af[mi] = *(const bf16x8*)(As + (m0 + mi*16 + li) * 32 + quad * 8);
#pragma unroll
      for (int ni = 0; ni < 4; ++ni)
        bg[ni] = *(const bf16x8*)(Bs + (n0 + ni*16 + li) * 32 + quad * 8);
#pragma unroll
      for (int mi = 0; mi < 4; ++mi)
#pragma unroll
        for (int ni = 0; ni < 4; ++ni)
          acc[mi][ni] = __builtin_amdgcn_mfma_f32_16x16x32_bf16(af[mi], bg[ni], acc[mi][ni], 0, 0, 0);
    }
  }

  const float* qb = q + (size_t)b * QSTRIDE + WOFF;
  float* ob = out + (size_t)b * 128 * 1024 + p0;
#pragma unroll
  for (int mi = 0; mi < 4; ++mi) {
    int o0 = m0 + mi*16 + quad*4;
    float4 bias = *(const float4*)(qb + o0);
#pragma unroll
    for (int ni = 0; ni < 4; ++ni) {
      int pl = n0 + ni*16 + li;
      float* dp = ob + (size_t)o0 * 1024 + pl;
      f32x4 a = acc[mi][ni];
      dp[0]    = a.x + bias.x;
      dp[1024] = a.y + bias.y;
      dp[2048] = a.z + bias.z;
      dp[3072] = a.w + bias.w;
    }
  }
}

extern "C" void kernel_launch(void* const* d_in, const int* in_sizes, int n_in,
                              void* d_out, int out_size, void* d_ws, size_t ws_size,
                              hipStream_t stream) {
  const float* q   = (const float*)d_in[0];
  const float* lhs = (const float*)d_in[1];
  const float* rhs = (const float*)d_in[2];
  const float* pw  = (const float*)d_in[3];
  const float* pb  = (const float*)d_in[4];
  float* out = (float*)d_out;

  // workspace layout (37,879,808 B total)
  char* ws = (char*)d_ws;
  ushort* wt2  = (ushort*)(ws);               // 18,874,368 B : wt2[b][tap][cq][o][32]
  ushort* pwb2 = (ushort*)(ws + 18874368);    //     65,536 B : pwb2[cq][o][32]
  ushort* xp2  = (ushort*)(ws + 18939904);    // 18,939,904 B : xp2[b][cq][34][34][32]

  pack_w_kernel     <<<512, 256, 0, stream>>>(q, wt2);
  pack_pw_kernel    <<<16,  256, 0, stream>>>(pw, pwb2);
  zero_border_kernel<<<64,  256, 0, stream>>>(xp2);
  proj_kernel       <<<dim3(8, 64), 256, 0, stream>>>(pwb2, lhs, rhs, pb, xp2);
  conv_kernel       <<<dim3(8, 64), 256, 0, stream>>>(wt2, xp2, q, out);
}

// Round 3
// 181.491 us; speedup vs baseline: 1.3768x; 1.0951x over previous
//
#include <hip/hip_runtime.h>
#include <hip/hip_bf16.h>

// Problem constants
#define QSTRIDE 147584   // per-sample question_rep stride (128*128*9 + 128)
#define WOFF    147456   // bias offset within question_rep row

typedef __attribute__((ext_vector_type(8))) short bf16x8;
typedef __attribute__((ext_vector_type(4))) float f32x4;

static __device__ __forceinline__ ushort f2bf(float f) {
  union { float f; unsigned u; } x; x.f = f;
  unsigned r = x.u + 0x7fffu + ((x.u >> 16) & 1u);  // RNE bf16 (finite inputs)
  return (ushort)(r >> 16);
}
static __device__ __forceinline__ unsigned pk2(ushort a, ushort b) {
  return (unsigned)a | ((unsigned)b << 16);
}
// async global->LDS DMA: 16B per active lane, lands at ldsbase + lane*16
static __device__ __forceinline__ void async16(const ushort* g, ushort* l) {
  __builtin_amdgcn_global_load_lds((const __attribute__((address_space(1))) void*)g,
                                   (__attribute__((address_space(3))) void*)l, 16, 0, 0);
}

// ---------------------------------------------------------------------------
// 1) question_rep weights -> wt2[b][tap][cq][o][ci32] bf16
//    LDS-staged: coalesced 256B/wave global reads, per-thread pick from LDS.
//    block = (b, ogrp of 16 o's); 4 rounds of 4 o's each.
// ---------------------------------------------------------------------------
__global__ __launch_bounds__(256) void pack_w_kernel(const float* __restrict__ q,
                                                     ushort* __restrict__ wt2) {
  __shared__ float Ls[4608];                 // 4 o's x 1152 floats
  int b = blockIdx.x >> 3, ogrp = blockIdx.x & 7;
  int t = threadIdx.x;
  const float* gbase = q + (size_t)b * QSTRIDE + (size_t)ogrp * 16 * 1152;
  ushort* dstb = wt2 + (size_t)b * 147456;
  int o_loc = t >> 6;                        // wave id = local o
  int ci    = (t & 63) * 2;                  // 2 channels per thread
  int cq    = ci >> 5, coff = ci & 31;
  for (int r = 0; r < 4; ++r) {
    __syncthreads();                         // previous round's LDS reads done
    const float* gs = gbase + r * 4608;
#pragma unroll
    for (int i = 0; i < 18; ++i) Ls[i * 256 + t] = gs[i * 256 + t];
    __syncthreads();
    int o_full = ogrp * 16 + r * 4 + o_loc;
    const float* v = Ls + o_loc * 1152 + ci * 9;   // 18 consecutive floats
    float a[18];
#pragma unroll
    for (int i = 0; i < 18; ++i) a[i] = v[i];
    ushort* dd = dstb + (size_t)cq * 4096 + o_full * 32 + coff;
#pragma unroll
    for (int tap = 0; tap < 9; ++tap) {
      unsigned pkv = pk2(f2bf(a[tap]), f2bf(a[9 + tap]));  // {ci, ci+1}
      *(unsigned*)(dd + (size_t)tap * 16384) = pkv;
    }
  }
}

// ---------------------------------------------------------------------------
// 2) proj_w (128x256 fp32) -> pwb2[cq][o][c32] bf16 (chunk-major, DMA-able)
// ---------------------------------------------------------------------------
__global__ __launch_bounds__(256) void pack_pw_kernel(const float* __restrict__ pw,
                                                      ushort* __restrict__ pwb2) {
  int tg = blockIdx.x * 256 + threadIdx.x;   // 4096 threads
  int o  = tg >> 5;
  int c0 = (tg & 31) * 8;
  const float4* s4 = (const float4*)(pw + (size_t)o * 256 + c0);
  float4 f0 = s4[0], f1 = s4[1];
  uint4 pkv;
  pkv.x = pk2(f2bf(f0.x), f2bf(f0.y)); pkv.y = pk2(f2bf(f0.z), f2bf(f0.w));
  pkv.z = pk2(f2bf(f1.x), f2bf(f1.y)); pkv.w = pk2(f2bf(f1.z), f2bf(f1.w));
  *(uint4*)(pwb2 + (size_t)(c0 >> 5) * 4096 + o * 32 + (c0 & 31)) = pkv;
}

// ---------------------------------------------------------------------------
// 3) zero the halo of xp2[b][cq][34][34][32]
// ---------------------------------------------------------------------------
__global__ __launch_bounds__(256) void zero_border_kernel(ushort* __restrict__ xp2) {
  int b = blockIdx.x, t = threadIdx.x;
  for (int idx = t; idx < 528; idx += 256) {
    int cq = idx / 132, r = idx - cq * 132;
    int hp, wp;
    if (r < 34)       { hp = 0;        wp = r; }
    else if (r < 68)  { hp = 33;       wp = r - 34; }
    else if (r < 100) { hp = r - 67;   wp = 0; }     // 1..32
    else              { hp = r - 99;   wp = 33; }    // 1..32
    uint4 z = {0u,0u,0u,0u};
    uint4* dst = (uint4*)(xp2 + (((size_t)b * 4 + cq) * 1156 + hp * 34 + wp) * 32);
#pragma unroll
    for (int i = 0; i < 4; ++i) dst[i] = z;
  }
}

// ---------------------------------------------------------------------------
// 4) Fused projection: reads lhs/rhs NCHW fp32 directly, register-transposes
//    into B-tiles, MFMA GEMM (M=128 o, N=128 px, K=256), writes xp2 bf16 NHWC.
// ---------------------------------------------------------------------------
__global__ __launch_bounds__(256, 2) void proj_kernel(const ushort* __restrict__ pwb2,
                                                      const float* __restrict__ lhs,
                                                      const float* __restrict__ rhs,
                                                      const float* __restrict__ pb,
                                                      ushort* __restrict__ xp2) {
  __shared__ ushort As[128 * 32];
  __shared__ ushort Bs[128 * 32];
  int b = blockIdx.y, tile = blockIdx.x;
  int p0 = tile * 128;
  int t = threadIdx.x;
  int lane = t & 63, wv = t >> 6;
  int m0 = (wv & 1) * 64, n0 = (wv >> 1) * 64;
  int quad = lane >> 4, li = lane & 15;
  f32x4 acc[4][4] = {};
  int cgrp = t & 3;                 // 8-channel group within 32-chunk
  int pq   = t >> 2;                // 0..63 -> pixel pair 2pq, 2pq+1

  for (int c0 = 0; c0 < 256; c0 += 32) {
    const float* src = (c0 < 128 ? lhs : rhs) + (size_t)b * 131072
                     + (size_t)((c0 & 127) + cgrp * 8) * 1024 + p0 + 2 * pq;
    ushort u0[8], u1[8];
#pragma unroll
    for (int j = 0; j < 8; ++j) {
      float2 f = *(const float2*)(src + (size_t)j * 1024);
      u0[j] = f2bf(f.x); u1[j] = f2bf(f.y);
    }
    __syncthreads();   // previous chunk fully consumed
    {
      const ushort* ag = pwb2 + (size_t)(c0 >> 5) * 4096;
      async16(ag + (size_t)wv * 512 + lane * 8,       As + wv * 512);
      async16(ag + (size_t)(wv + 4) * 512 + lane * 8, As + (wv + 4) * 512);
    }
    {
      uint4 pk0, pk1;
      pk0.x = pk2(u0[0],u0[1]); pk0.y = pk2(u0[2],u0[3]);
      pk0.z = pk2(u0[4],u0[5]); pk0.w = pk2(u0[6],u0[7]);
      pk1.x = pk2(u1[0],u1[1]); pk1.y = pk2(u1[2],u1[3]);
      pk1.z = pk2(u1[4],u1[5]); pk1.w = pk2(u1[6],u1[7]);
      *(uint4*)(Bs + (size_t)(2*pq)   * 32 + cgrp * 8) = pk0;
      *(uint4*)(Bs + (size_t)(2*pq+1) * 32 + cgrp * 8) = pk1;
    }
    __syncthreads();   // drains DMA (vmcnt) + LDS stores
    bf16x8 af[4], bg[4];
#pragma unroll
    for (int mi = 0; mi < 4; ++mi)
      af[mi] = *(const bf16x8*)(As + (m0 + mi*16 + li) * 32 + quad * 8);
#pragma unroll
    for (int ni = 0; ni < 4; ++ni)
      bg[ni] = *(const bf16x8*)(Bs + (n0 + ni*16 + li) * 32 + quad * 8);
#pragma unroll
    for (int mi = 0; mi < 4; ++mi)
#pragma unroll
      for (int ni = 0; ni < 4; ++ni)
        acc[mi][ni] = __builtin_amdgcn_mfma_f32_16x16x32_bf16(af[mi], bg[ni], acc[mi][ni], 0, 0, 0);
  }

  ushort* xpb = xp2 + (size_t)b * 4 * 1156 * 32;
#pragma unroll
  for (int mi = 0; mi < 4; ++mi) {
    int o0 = m0 + mi*16 + quad*4;
    float4 bias = *(const float4*)(pb + o0);
#pragma unroll
    for (int ni = 0; ni < 4; ++ni) {
      int p = p0 + n0 + ni*16 + li;
      int h = p >> 5, w = p & 31;
      ushort* dp = xpb + ((size_t)(o0 >> 5) * 1156 + (h + 1) * 34 + (w + 1)) * 32 + (o0 & 31);
      f32x4 a = acc[mi][ni];
      uint2 pkv;
      pkv.x = pk2(f2bf(a.x + bias.x), f2bf(a.y + bias.y));
      pkv.y = pk2(f2bf(a.z + bias.z), f2bf(a.w + bias.w));
      *(uint2*)dp = pkv;
    }
  }
}

// ---------------------------------------------------------------------------
// 5) Conv implicit GEMM, cq-outer / tap-inner:
//    - B super-tile (6 rows x 34 px, 13KB) staged ONCE per cq, reused by 9 taps
//    - A (8KB per tap) double-buffered, prefetched right after the barrier
//    - b = blk&63: the 8 tile-blocks of a sample share one XCD's L2 for wt2
// ---------------------------------------------------------------------------
__global__ __launch_bounds__(256, 2) void conv_kernel(const ushort* __restrict__ wt2,
                                                      const ushort* __restrict__ xp2,
                                                      const float* __restrict__ q,
                                                      float* __restrict__ out) {
  __shared__ ushort As[2][4096];
  __shared__ ushort Bs[6528];                // 6*34*32
  int blk = blockIdx.x;
  int b = blk & 63, tile = blk >> 6;
  int p0 = tile * 128, h0 = tile * 4;
  int t = threadIdx.x;
  int lane = t & 63, wv = t >> 6;
  int m0 = (wv & 1) * 64, n0 = (wv >> 1) * 64;
  int quad = lane >> 4, li = lane & 15;
  f32x4 acc[4][4] = {};
  const ushort* wtb = wt2 + (size_t)b * 147456;
  const ushort* xpb = xp2 + (size_t)b * 147968;   // 4*1156*32

  for (int cq = 0; cq < 4; ++cq) {
    __syncthreads();                         // prior compute's LDS reads done
    // stage B super-tile: one linear 13,056B copy (816 x 16B)
    {
      const ushort* bgp = xpb + (size_t)(cq * 1156 + h0 * 34) * 32;
#pragma unroll
      for (int p = 0; p < 3; ++p)
        async16(bgp + (size_t)(p * 256 + t) * 8, Bs + p * 2048 + wv * 512);
      if (t < 48)                            // wv==0: tail 48 lanes
        async16(bgp + (size_t)(768 + t) * 8, Bs + 6144);
    }
    // stage A(cq, tap=0) -> As[0]
    {
      const ushort* ag = wtb + (size_t)cq * 4096;
      async16(ag + (size_t)t * 8,         As[0] + wv * 512);
      async16(ag + (size_t)(256 + t) * 8, As[0] + 2048 + wv * 512);
    }
    for (int tap = 0; tap < 9; ++tap) {
      __syncthreads();                       // vmcnt(0) drain: staged data visible
      if (tap < 8) {                         // prefetch next tap's A (overlaps MFMA)
        const ushort* ag = wtb + (size_t)((tap + 1) * 4 + cq) * 4096;
        ushort* ab = As[(tap + 1) & 1];
        async16(ag + (size_t)t * 8,         ab + wv * 512);
        async16(ag + (size_t)(256 + t) * 8, ab + 2048 + wv * 512);
      }
      int kh = tap / 3, kw = tap - kh * 3;
      const ushort* ar = As[tap & 1];
      bf16x8 af[4], bg[4];
#pragma unroll
      for (int mi = 0; mi < 4; ++mi)
        af[mi] = *(const bf16x8*)(ar + (m0 + mi*16 + li) * 32 + quad * 8);
#pragma unroll
      for (int ni = 0; ni < 4; ++ni) {
        int pl = n0 + ni*16 + li;
        int h = pl >> 5, w = pl & 31;
        bg[ni] = *(const bf16x8*)(Bs + ((h + kh) * 34 + (w + kw)) * 32 + quad * 8);
      }
#pragma unroll
      for (int mi = 0; mi < 4; ++mi)
#pragma unroll
        for (int ni = 0; ni < 4; ++ni)
          acc[mi][ni] = __builtin_amdgcn_mfma_f32_16x16x32_bf16(af[mi], bg[ni], acc[mi][ni], 0, 0, 0);
    }
  }

  const float* qb = q + (size_t)b * QSTRIDE + WOFF;
  float* ob = out + (size_t)b * 128 * 1024 + p0;
#pragma unroll
  for (int mi = 0; mi < 4; ++mi) {
    int o0 = m0 + mi*16 + quad*4;
    float4 bias = *(const float4*)(qb + o0);
#pragma unroll
    for (int ni = 0; ni < 4; ++ni) {
      int pl = n0 + ni*16 + li;
      float* dp = ob + (size_t)o0 * 1024 + pl;
      f32x4 a = acc[mi][ni];
      dp[0]    = a.x + bias.x;
      dp[1024] = a.y + bias.y;
      dp[2048] = a.z + bias.z;
      dp[3072] = a.w + bias.w;
    }
  }
}

extern "C" void kernel_launch(void* const* d_in, const int* in_sizes, int n_in,
                              void* d_out, int out_size, void* d_ws, size_t ws_size,
                              hipStream_t stream) {
  const float* q   = (const float*)d_in[0];
  const float* lhs = (const float*)d_in[1];
  const float* rhs = (const float*)d_in[2];
  const float* pw  = (const float*)d_in[3];
  const float* pb  = (const float*)d_in[4];
  float* out = (float*)d_out;

  // workspace layout (37,879,808 B total)
  char* ws = (char*)d_ws;
  ushort* wt2  = (ushort*)(ws);               // 18,874,368 B : wt2[b][tap][cq][o][32]
  ushort* pwb2 = (ushort*)(ws + 18874368);    //     65,536 B : pwb2[cq][o][32]
  ushort* xp2  = (ushort*)(ws + 18939904);    // 18,939,904 B : xp2[b][cq][34][34][32]

  pack_w_kernel     <<<512, 256, 0, stream>>>(q, wt2);
  pack_pw_kernel    <<<16,  256, 0, stream>>>(pw, pwb2);
  zero_border_kernel<<<64,  256, 0, stream>>>(xp2);
  proj_kernel       <<<dim3(8, 64), 256, 0, stream>>>(pwb2, lhs, rhs, pb, xp2);
  conv_kernel       <<<512, 256, 0, stream>>>(wt2, xp2, q, out);
}